// Round 1
// baseline (1145.044 us; speedup 1.0000x reference)
//
#include <hip/hip_runtime.h>

constexpr int B = 64, T = 128, M = 8, KLEAF = 5, KR = 6, N = 48, E = 16, H = 32;
constexpr int BNR = B * N;              // 3072 rows
constexpr int NG  = B * T;              // 8192 graphs
constexpr long long R_SIZE = (long long)B * T * N * H;  // 12582912

#define DEVI __device__ __forceinline__

DEVI float frcp(float x) { return __builtin_amdgcn_rcpf(x); }
DEVI float sigm(float x) { return frcp(1.f + __expf(-x)); }
DEVI float tanh_(float x) {
  float a = __expf(2.f * fabsf(x));
  float r = 1.f - 2.f * frcp(a + 1.f);
  return x >= 0.f ? r : -r;
}

// ---------------- K1: root aggregation + phi MLP → v_ws (T, B*N, E) ----------
__global__ __launch_bounds__(256) void k_phi(
    const float* __restrict__ feat, const float* __restrict__ w1,
    const float* __restrict__ b1, const float* __restrict__ w2,
    const float* __restrict__ b2, float* __restrict__ v_ws)
{
  int gid = blockIdx.x * 256 + threadIdx.x;
  if (gid >= B * T * N) return;
  int nn = gid % N;        // node within graph = m*KR + k
  int bt = gid / N;        // b*T + t
  int m = nn / KR, k = nn % KR;
  int t = bt % T, b = bt / T;
  const float* fp = feat + ((size_t)bt * M + m) * (KLEAF * 3);
  float x0, x1, x2;
  if (k < KLEAF) {
    x0 = fp[k * 3 + 0]; x1 = fp[k * 3 + 1]; x2 = fp[k * 3 + 2];
  } else {
    float sx = 0.f, sy = 0.f, sw = 0.f, av = 0.f;
#pragma unroll
    for (int kp = 0; kp < KLEAF; kp++) {
      float fx = fp[kp * 3], fy = fp[kp * 3 + 1], fv = fp[kp * 3 + 2];
      float w = fv > 0.5f ? 1.f : 0.f;
      sx += fx * w; sy += fy * w; sw += w; av = fmaxf(av, w);
    }
    float dn = fmaxf(sw, 1.f);
    x0 = sx / dn; x1 = sy / dn; x2 = av;
  }
  float hd[E];
#pragma unroll
  for (int e = 0; e < E; e++) {
    float v = b1[e] + x0 * w1[0 * E + e] + x1 * w1[1 * E + e] + x2 * w1[2 * E + e];
    hd[e] = v > 0.f ? v : 0.f;
  }
  float* vo = v_ws + ((size_t)t * BNR + (size_t)b * N + nn) * E;
#pragma unroll
  for (int e2 = 0; e2 < E; e2++) {
    float acc = b2[e2];
#pragma unroll
    for (int e = 0; e < E; e++) acc += hd[e] * w2[e * E + e2];
    vo[e2] = acc;
  }
}

// ------------- K2: spatial LSTM. 1 wave/block, 2 rows/wave, 32 lanes/row -----
// Writes r to d_out[0:R] (B,T,N,H) and to h-part first half (B,T,N,2H).
__global__ __launch_bounds__(64, 2) void k_lstm1(
    const float* __restrict__ v_ws, const float* __restrict__ wih,
    const float* __restrict__ whh, const float* __restrict__ bih,
    const float* __restrict__ bhh, float* __restrict__ dout)
{
  int lane = threadIdx.x;
  int sub = lane & 31, half = lane >> 5;
  int row = blockIdx.x * 2 + half;
  int b = row / N, n = row % N;
  float Wx[4][E], Wh[4][H], bs[4];
#pragma unroll
  for (int g = 0; g < 4; g++) {
    int gi = g * H + sub;
#pragma unroll
    for (int e = 0; e < E; e++) Wx[g][e] = wih[gi * E + e];
#pragma unroll
    for (int kk = 0; kk < H; kk++) Wh[g][kk] = whh[gi * H + kk];
    bs[g] = bih[gi] + bhh[gi];
  }
  float h = 0.f, c = 0.f;
  const float* xp = v_ws + (size_t)row * E + sub;
  float* pr = dout + (size_t)b * T * N * H + (size_t)n * H + sub;
  float* ph = dout + R_SIZE + (size_t)b * T * N * 2 * H + (size_t)n * 2 * H + sub;
  for (int t = 0; t < T; t++) {
    float xv = (sub < E) ? xp[(size_t)t * BNR * E] : 0.f;
    float a0 = bs[0], a1 = bs[1], a2 = bs[2], a3 = bs[3];
#pragma unroll
    for (int e = 0; e < E; e++) {
      float xe = __shfl(xv, e, 32);
      a0 += Wx[0][e] * xe; a1 += Wx[1][e] * xe; a2 += Wx[2][e] * xe; a3 += Wx[3][e] * xe;
    }
#pragma unroll
    for (int kk = 0; kk < H; kk++) {
      float hk = __shfl(h, kk, 32);
      a0 += Wh[0][kk] * hk; a1 += Wh[1][kk] * hk; a2 += Wh[2][kk] * hk; a3 += Wh[3][kk] * hk;
    }
    float ig = sigm(a0), fg = sigm(a1), gv = tanh_(a2), og = sigm(a3);
    c = fg * c + ig * gv;
    h = og * tanh_(c);
    pr[(size_t)t * N * H] = h;
    ph[(size_t)t * N * 2 * H] = h;
  }
}

// ---------------- K3: BatchNorm per t over (B*N, H) → bn_ws (B*T, N, H) ------
__global__ __launch_bounds__(256) void k_bn(
    const float* __restrict__ r, const float* __restrict__ gamma,
    const float* __restrict__ beta, float* __restrict__ bn_ws)
{
  int t = blockIdx.x;
  int c = threadIdx.x & 31;
  int rg = threadIdx.x >> 5;   // 0..7
  float s = 0.f, s2 = 0.f;
  for (int row = rg; row < BNR; row += 8) {
    int b = row / N, n = row % N;
    float x = r[((size_t)b * T + t) * N * H + (size_t)n * H + c];
    s += x; s2 += x * x;
  }
  __shared__ float sm[2][8][32];
  sm[0][rg][c] = s; sm[1][rg][c] = s2;
  __syncthreads();
  __shared__ float st[2][32];
  if (rg == 0) {
    float ss = 0.f, ss2 = 0.f;
#pragma unroll
    for (int i = 0; i < 8; i++) { ss += sm[0][i][c]; ss2 += sm[1][i][c]; }
    float mu = ss * (1.f / BNR);
    float var = ss2 * (1.f / BNR) - mu * mu;
    float rstd = rsqrtf(var + 1e-5f);
    float sc = gamma[c] * rstd;
    st[0][c] = sc;
    st[1][c] = beta[c] - mu * sc;
  }
  __syncthreads();
  float sc = st[0][c], sh = st[1][c];
  for (int row = rg; row < BNR; row += 8) {
    int b = row / N, n = row % N;
    size_t idx = ((size_t)b * T + t) * N * H + (size_t)n * H + c;
    bn_ws[idx] = r[idx] * sc + sh;
  }
}

// ------------- K4: fused 2x GAT per graph (block = graph) → gat_ws (T,B*N,H) -
__global__ __launch_bounds__(256) void k_gat(
    const float* __restrict__ bn_ws,
    const float* __restrict__ w1, const float* __restrict__ a1, const float* __restrict__ bg1,
    const float* __restrict__ w2, const float* __restrict__ a2, const float* __restrict__ bg2,
    float* __restrict__ gat_ws)
{
  int g = blockIdx.x;          // b*T + t
  int b = g >> 7, t = g & 127;
  int tid = threadIdx.x;
  __shared__ float X[N][H];
  __shared__ float Hm[N][H + 1];   // padded: row-reads conflict-free
  __shared__ float Wl[H * H];
  __shared__ float ssrc[N], sdst[N];
  __shared__ float alph[M][12];
  for (int i = tid; i < N * H; i += 256) ((float*)X)[i] = bn_ws[(size_t)g * N * H + i];
  const float* Ws[2] = {w1, w2};
  const float* As[2] = {a1, a2};
  const float* Bs[2] = {bg1, bg2};
  int oc = tid & 31, n0 = tid >> 5;
  for (int layer = 0; layer < 2; layer++) {
    const float* av = As[layer];
    const float* bias = Bs[layer];
    for (int i = tid; i < H * H; i += 256) Wl[i] = Ws[layer][i];
    __syncthreads();
    // h = X @ W  (48x32 @ 32x32)
#pragma unroll
    for (int rep = 0; rep < 6; rep++) {
      int n = n0 + rep * 8;
      float acc = 0.f;
#pragma unroll
      for (int kk = 0; kk < H; kk++) acc += X[n][kk] * Wl[kk * H + oc];
      Hm[n][oc] = acc;
    }
    __syncthreads();
    if (tid < N) {
      float as = 0.f, ad = 0.f;
#pragma unroll
      for (int kk = 0; kk < H; kk++) {
        float x = Hm[tid][kk];
        as += x * av[kk]; ad += x * av[H + kk];
      }
      ssrc[tid] = as; sdst[tid] = ad;
    }
    __syncthreads();
    if (tid < M) {   // softmax over each root's 12 incoming edges
      float ev[12];
      float sd = sdst[tid * KR + KR - 1];
#pragma unroll
      for (int kp = 0; kp < KLEAF; kp++) ev[kp] = ssrc[tid * KR + kp] + sd;
#pragma unroll
      for (int j = 0; j < 7; j++) {
        int mm = j < tid ? j : j + 1;
        ev[KLEAF + j] = ssrc[mm * KR + KR - 1] + sd;
      }
      float mx = -1e30f;
#pragma unroll
      for (int i = 0; i < 12; i++) {
        float e = ev[i]; e = e > 0.f ? e : 0.2f * e;
        ev[i] = e; mx = fmaxf(mx, e);
      }
      float s = 0.f;
#pragma unroll
      for (int i = 0; i < 12; i++) { float e = __expf(ev[i] - mx); ev[i] = e; s += e; }
      float inv = frcp(s);
#pragma unroll
      for (int i = 0; i < 12; i++) alph[tid][i] = ev[i] * inv;
    }
    __syncthreads();
    float hv[6];
#pragma unroll
    for (int rep = 0; rep < 6; rep++) {
      int n = n0 + rep * 8;
      int m2 = n / KR;
      float acc;
      if (n % KR == KR - 1) {      // root: attention-weighted sum of 12 srcs
        acc = 0.f;
#pragma unroll
        for (int kp = 0; kp < KLEAF; kp++) acc += alph[m2][kp] * Hm[m2 * KR + kp][oc];
#pragma unroll
        for (int j = 0; j < 7; j++) {
          int mm = j < m2 ? j : j + 1;
          acc += alph[m2][KLEAF + j] * Hm[mm * KR + KR - 1][oc];
        }
      } else {                      // leaf: single incoming edge, alpha == 1
        acc = Hm[m2 * KR + KR - 1][oc];
      }
      acc += bias[oc];
      hv[rep] = acc > 0.f ? acc : __expf(acc) - 1.f;   // elu
    }
    __syncthreads();
#pragma unroll
    for (int rep = 0; rep < 6; rep++) X[n0 + rep * 8][oc] = hv[rep];
    __syncthreads();
  }
  for (int i = tid; i < N * H; i += 256)
    gat_ws[((size_t)t * BNR + (size_t)b * N) * H + i] = ((float*)X)[i];
}

// ------------- K5: temporal LSTM → l into h-part second half -----------------
__global__ __launch_bounds__(64, 1) void k_lstm2(
    const float* __restrict__ gat_ws, const float* __restrict__ wih,
    const float* __restrict__ whh, const float* __restrict__ bih,
    const float* __restrict__ bhh, float* __restrict__ dout)
{
  int lane = threadIdx.x;
  int sub = lane & 31, half = lane >> 5;
  int row = blockIdx.x * 2 + half;
  int b = row / N, n = row % N;
  float Wx[4][H], Wh[4][H], bs[4];
#pragma unroll
  for (int g = 0; g < 4; g++) {
    int gi = g * H + sub;
#pragma unroll
    for (int e = 0; e < H; e++) Wx[g][e] = wih[gi * H + e];
#pragma unroll
    for (int kk = 0; kk < H; kk++) Wh[g][kk] = whh[gi * H + kk];
    bs[g] = bih[gi] + bhh[gi];
  }
  float h = 0.f, c = 0.f;
  const float* xp = gat_ws + (size_t)row * H + sub;
  float* pl = dout + R_SIZE + (size_t)b * T * N * 2 * H + (size_t)n * 2 * H + H + sub;
  for (int t = 0; t < T; t++) {
    float xv = xp[(size_t)t * BNR * H];
    float a0 = bs[0], a1 = bs[1], a2 = bs[2], a3 = bs[3];
#pragma unroll
    for (int e = 0; e < H; e++) {
      float xe = __shfl(xv, e, 32);
      a0 += Wx[0][e] * xe; a1 += Wx[1][e] * xe; a2 += Wx[2][e] * xe; a3 += Wx[3][e] * xe;
    }
#pragma unroll
    for (int kk = 0; kk < H; kk++) {
      float hk = __shfl(h, kk, 32);
      a0 += Wh[0][kk] * hk; a1 += Wh[1][kk] * hk; a2 += Wh[2][kk] * hk; a3 += Wh[3][kk] * hk;
    }
    float ig = sigm(a0), fg = sigm(a1), gv = tanh_(a2), og = sigm(a3);
    c = fg * c + ig * gv;
    h = og * tanh_(c);
    pl[(size_t)t * N * 2 * H] = h;
  }
}

extern "C" void kernel_launch(void* const* d_in, const int* in_sizes, int n_in,
                              void* d_out, int out_size, void* d_ws, size_t ws_size,
                              hipStream_t stream)
{
  const float* feat     = (const float*)d_in[0];
  const float* phi_w1   = (const float*)d_in[1];
  const float* phi_b1   = (const float*)d_in[2];
  const float* phi_w2   = (const float*)d_in[3];
  const float* phi_b2   = (const float*)d_in[4];
  const float* spa_wih  = (const float*)d_in[5];
  const float* spa_whh  = (const float*)d_in[6];
  const float* spa_bih  = (const float*)d_in[7];
  const float* spa_bhh  = (const float*)d_in[8];
  const float* bn_gamma = (const float*)d_in[9];
  const float* bn_beta  = (const float*)d_in[10];
  const float* gat1_w   = (const float*)d_in[11];
  const float* gat1_a   = (const float*)d_in[12];
  const float* gat1_b   = (const float*)d_in[13];
  const float* gat2_w   = (const float*)d_in[14];
  const float* gat2_a   = (const float*)d_in[15];
  const float* gat2_b   = (const float*)d_in[16];
  const float* temp_wih = (const float*)d_in[17];
  const float* temp_whh = (const float*)d_in[18];
  const float* temp_bih = (const float*)d_in[19];
  const float* temp_bhh = (const float*)d_in[20];
  float* out = (float*)d_out;

  float* v_ws   = (float*)d_ws;                     // T*BNR*E   = 6.29M floats
  float* bn_ws  = v_ws  + (size_t)T * BNR * E;      // B*T*N*H   = 12.58M floats
  float* gat_ws = bn_ws + (size_t)B * T * N * H;    // T*BNR*H   = 12.58M floats

  k_phi  <<<(B * T * N + 255) / 256, 256, 0, stream>>>(feat, phi_w1, phi_b1, phi_w2, phi_b2, v_ws);
  k_lstm1<<<BNR / 2, 64, 0, stream>>>(v_ws, spa_wih, spa_whh, spa_bih, spa_bhh, out);
  k_bn   <<<T, 256, 0, stream>>>(out, bn_gamma, bn_beta, bn_ws);
  k_gat  <<<NG, 256, 0, stream>>>(bn_ws, gat1_w, gat1_a, gat1_b, gat2_w, gat2_a, gat2_b, gat_ws);
  k_lstm2<<<BNR / 2, 64, 0, stream>>>(gat_ws, temp_wih, temp_whh, temp_bih, temp_bhh, out);
}

// Round 2
// 591.799 us; speedup vs baseline: 1.9349x; 1.9349x over previous
//
#include <hip/hip_runtime.h>

constexpr int B = 64, T = 128, M = 8, KLEAF = 5, KR = 6, N = 48, E = 16, H = 32;
constexpr int BNR = B * N;              // 3072 rows
constexpr int NG  = B * T;              // 8192 graphs
constexpr long long R_SIZE = (long long)B * T * N * H;  // 12582912

#define DEVI __device__ __forceinline__

DEVI float frcp(float x) { return __builtin_amdgcn_rcpf(x); }
DEVI float sigm(float x) { return frcp(1.f + __expf(-x)); }
DEVI float tanh_(float x) {
  float a = __expf(2.f * fabsf(x));
  float r = 1.f - 2.f * frcp(a + 1.f);
  return x >= 0.f ? r : -r;
}

// ---------------- K1: root aggregation + phi MLP → v_ws (T, B*N, E) ----------
__global__ __launch_bounds__(256) void k_phi(
    const float* __restrict__ feat, const float* __restrict__ w1,
    const float* __restrict__ b1, const float* __restrict__ w2,
    const float* __restrict__ b2, float* __restrict__ v_ws)
{
  int gid = blockIdx.x * 256 + threadIdx.x;
  if (gid >= B * T * N) return;
  int nn = gid % N;        // node within graph = m*KR + k
  int bt = gid / N;        // b*T + t
  int m = nn / KR, k = nn % KR;
  int t = bt % T, b = bt / T;
  const float* fp = feat + ((size_t)bt * M + m) * (KLEAF * 3);
  float x0, x1, x2;
  if (k < KLEAF) {
    x0 = fp[k * 3 + 0]; x1 = fp[k * 3 + 1]; x2 = fp[k * 3 + 2];
  } else {
    float sx = 0.f, sy = 0.f, sw = 0.f, av = 0.f;
#pragma unroll
    for (int kp = 0; kp < KLEAF; kp++) {
      float fx = fp[kp * 3], fy = fp[kp * 3 + 1], fv = fp[kp * 3 + 2];
      float w = fv > 0.5f ? 1.f : 0.f;
      sx += fx * w; sy += fy * w; sw += w; av = fmaxf(av, w);
    }
    float dn = fmaxf(sw, 1.f);
    x0 = sx / dn; x1 = sy / dn; x2 = av;
  }
  float hd[E];
#pragma unroll
  for (int e = 0; e < E; e++) {
    float v = b1[e] + x0 * w1[0 * E + e] + x1 * w1[1 * E + e] + x2 * w1[2 * E + e];
    hd[e] = v > 0.f ? v : 0.f;
  }
  float* vo = v_ws + ((size_t)t * BNR + (size_t)b * N + nn) * E;
#pragma unroll
  for (int e2 = 0; e2 < E; e2++) {
    float acc = b2[e2];
#pragma unroll
    for (int e = 0; e < E; e++) acc += hd[e] * w2[e * E + e2];
    vo[e2] = acc;
  }
}

// ------------- K2/K5: LSTM, 1 row per 64-lane wave ---------------------------
// lane L: j = L&31, hi = L>>5. Lane computes gate rows gA = hi*32+j (i or f)
// and gB = 64+hi*32+j (g or o). h broadcast via per-wave LDS slot: high half
// writes h[j], all lanes read back as 8x ds_read_b128 (same-address broadcast,
// in-order DS within one wave -> no barrier needed). x rows prefetched one
// step ahead into registers (float4), latency hidden under the gate FMAs.
// MODE 0: lstm1 (write r and h-low-half). MODE 1: lstm2 (write h-high-half).
template <int EE, int MODE>
__global__ void __launch_bounds__(64, 2) k_lstm(
    const float* __restrict__ x, const float* __restrict__ wih,
    const float* __restrict__ whh, const float* __restrict__ bih,
    const float* __restrict__ bhh, float* __restrict__ dout)
{
  constexpr int X4 = EE / 4;
  int j = threadIdx.x & 31, hi = threadIdx.x >> 5;
  int row = blockIdx.x;
  int b = row / N, n = row % N;
  int gA = hi * 32 + j, gB = 64 + hi * 32 + j;

  float WxA[EE], WxB[EE], WhA[32], WhB[32];
#pragma unroll
  for (int e = 0; e < EE; e++) { WxA[e] = wih[gA * EE + e]; WxB[e] = wih[gB * EE + e]; }
#pragma unroll
  for (int k = 0; k < 32; k++) { WhA[k] = whh[gA * 32 + k]; WhB[k] = whh[gB * 32 + k]; }
  float bsA = bih[gA] + bhh[gA], bsB = bih[gB] + bhh[gB];

  __shared__ __align__(16) float hbuf[32];
  if (threadIdx.x < 32) hbuf[threadIdx.x] = 0.f;   // same wave: in-order DS

  float c = 0.f;
  const float4* xbase = (const float4*)(x + (size_t)row * EE);
  constexpr size_t XSTRIDE = (size_t)BNR * EE / 4;   // per-t stride in float4

  float* pr = dout + ((size_t)b * T * N + n) * H + j;
  float* ph = dout + R_SIZE + ((size_t)b * T * N + n) * 2 * H + (MODE == 1 ? H : 0) + j;

  float4 XC[X4], XN[X4];
#pragma unroll
  for (int q = 0; q < X4; q++) XC[q] = xbase[q];

  auto step = [&](int t, float4* Xc, float4* Xn) {
    // prefetch next x row (pure loads; vmcnt wait deferred to next step's use)
    int tn = t + 1 < T ? t + 1 : t;
    const float4* pxn = xbase + (size_t)tn * XSTRIDE;
#pragma unroll
    for (int q = 0; q < X4; q++) Xn[q] = pxn[q];
    float aA0 = bsA, aA1 = 0.f, aB0 = bsB, aB1 = 0.f;
#pragma unroll
    for (int q = 0; q < X4; q++) {
      float4 xv = Xc[q];
      aA0 += WxA[4 * q + 0] * xv.x; aA1 += WxA[4 * q + 1] * xv.y;
      aA0 += WxA[4 * q + 2] * xv.z; aA1 += WxA[4 * q + 3] * xv.w;
      aB0 += WxB[4 * q + 0] * xv.x; aB1 += WxB[4 * q + 1] * xv.y;
      aB0 += WxB[4 * q + 2] * xv.z; aB1 += WxB[4 * q + 3] * xv.w;
    }
    const float4* hb4 = (const float4*)hbuf;
#pragma unroll
    for (int q = 0; q < 8; q++) {
      float4 hv = hb4[q];      // ds_read_b128, all lanes same addr: broadcast
      aA0 += WhA[4 * q + 0] * hv.x; aA1 += WhA[4 * q + 1] * hv.y;
      aA0 += WhA[4 * q + 2] * hv.z; aA1 += WhA[4 * q + 3] * hv.w;
      aB0 += WhB[4 * q + 0] * hv.x; aB1 += WhB[4 * q + 1] * hv.y;
      aB0 += WhB[4 * q + 2] * hv.z; aB1 += WhB[4 * q + 3] * hv.w;
    }
    float aA = aA0 + aA1, aB = aB0 + aB1;
    float sA = sigm(aA);                       // lo: sigm(i) ; hi: sigm(f)
    float vB = hi ? sigm(aB) : tanh_(aB);      // lo: tanh(g) ; hi: sigm(o)
    float send = hi ? sA : sA * vB;            // hi sends sF ; lo sends i*g
    float recv = __shfl_xor(send, 32);
    float sF = hi ? sA : recv;
    float p  = hi ? recv : send;
    c = sF * c + p;
    float tc = tanh_(c);
    if (hi) {
      float h = vB * tc;
      hbuf[j] = h;
      if (MODE == 0) {
        pr[(size_t)t * N * H] = h;
        ph[(size_t)t * N * 2 * H] = h;
      } else {
        ph[(size_t)t * N * 2 * H] = h;
      }
    }
    __builtin_amdgcn_sched_barrier(0);  // keep h-write before next step's reads
  };

  for (int t = 0; t < T; t += 2) {
    step(t, XC, XN);
    step(t + 1, XN, XC);
  }
}

// ---------------- K3: BatchNorm per t over (B*N, H) → bn_ws (B*T, N, H) ------
__global__ __launch_bounds__(256) void k_bn(
    const float* __restrict__ r, const float* __restrict__ gamma,
    const float* __restrict__ beta, float* __restrict__ bn_ws)
{
  int t = blockIdx.x;
  int c = threadIdx.x & 31;
  int rg = threadIdx.x >> 5;   // 0..7
  float s = 0.f, s2 = 0.f;
  for (int row = rg; row < BNR; row += 8) {
    int b = row / N, n = row % N;
    float x = r[((size_t)b * T + t) * N * H + (size_t)n * H + c];
    s += x; s2 += x * x;
  }
  __shared__ float sm[2][8][32];
  sm[0][rg][c] = s; sm[1][rg][c] = s2;
  __syncthreads();
  __shared__ float st[2][32];
  if (rg == 0) {
    float ss = 0.f, ss2 = 0.f;
#pragma unroll
    for (int i = 0; i < 8; i++) { ss += sm[0][i][c]; ss2 += sm[1][i][c]; }
    float mu = ss * (1.f / BNR);
    float var = ss2 * (1.f / BNR) - mu * mu;
    float rstd = rsqrtf(var + 1e-5f);
    float sc = gamma[c] * rstd;
    st[0][c] = sc;
    st[1][c] = beta[c] - mu * sc;
  }
  __syncthreads();
  float sc = st[0][c], sh = st[1][c];
  for (int row = rg; row < BNR; row += 8) {
    int b = row / N, n = row % N;
    size_t idx = ((size_t)b * T + t) * N * H + (size_t)n * H + c;
    bn_ws[idx] = r[idx] * sc + sh;
  }
}

// ------------- K4: fused 2x GAT per graph (block = graph) → gat_ws (T,B*N,H) -
__global__ __launch_bounds__(256) void k_gat(
    const float* __restrict__ bn_ws,
    const float* __restrict__ w1, const float* __restrict__ a1, const float* __restrict__ bg1,
    const float* __restrict__ w2, const float* __restrict__ a2, const float* __restrict__ bg2,
    float* __restrict__ gat_ws)
{
  int g = blockIdx.x;          // b*T + t
  int b = g >> 7, t = g & 127;
  int tid = threadIdx.x;
  __shared__ float X[N][H];
  __shared__ float Hm[N][H + 1];   // padded: row-reads conflict-free
  __shared__ float Wl[H * H];
  __shared__ float ssrc[N], sdst[N];
  __shared__ float alph[M][12];
  for (int i = tid; i < N * H; i += 256) ((float*)X)[i] = bn_ws[(size_t)g * N * H + i];
  const float* Ws[2] = {w1, w2};
  const float* As[2] = {a1, a2};
  const float* Bs[2] = {bg1, bg2};
  int oc = tid & 31, n0 = tid >> 5;
  for (int layer = 0; layer < 2; layer++) {
    const float* av = As[layer];
    const float* bias = Bs[layer];
    for (int i = tid; i < H * H; i += 256) Wl[i] = Ws[layer][i];
    __syncthreads();
    // h = X @ W  (48x32 @ 32x32)
#pragma unroll
    for (int rep = 0; rep < 6; rep++) {
      int n = n0 + rep * 8;
      float acc = 0.f;
#pragma unroll
      for (int kk = 0; kk < H; kk++) acc += X[n][kk] * Wl[kk * H + oc];
      Hm[n][oc] = acc;
    }
    __syncthreads();
    if (tid < N) {
      float as = 0.f, ad = 0.f;
#pragma unroll
      for (int kk = 0; kk < H; kk++) {
        float x = Hm[tid][kk];
        as += x * av[kk]; ad += x * av[H + kk];
      }
      ssrc[tid] = as; sdst[tid] = ad;
    }
    __syncthreads();
    if (tid < M) {   // softmax over each root's 12 incoming edges
      float ev[12];
      float sd = sdst[tid * KR + KR - 1];
#pragma unroll
      for (int kp = 0; kp < KLEAF; kp++) ev[kp] = ssrc[tid * KR + kp] + sd;
#pragma unroll
      for (int j = 0; j < 7; j++) {
        int mm = j < tid ? j : j + 1;
        ev[KLEAF + j] = ssrc[mm * KR + KR - 1] + sd;
      }
      float mx = -1e30f;
#pragma unroll
      for (int i = 0; i < 12; i++) {
        float e = ev[i]; e = e > 0.f ? e : 0.2f * e;
        ev[i] = e; mx = fmaxf(mx, e);
      }
      float s = 0.f;
#pragma unroll
      for (int i = 0; i < 12; i++) { float e = __expf(ev[i] - mx); ev[i] = e; s += e; }
      float inv = frcp(s);
#pragma unroll
      for (int i = 0; i < 12; i++) alph[tid][i] = ev[i] * inv;
    }
    __syncthreads();
    float hv[6];
#pragma unroll
    for (int rep = 0; rep < 6; rep++) {
      int n = n0 + rep * 8;
      int m2 = n / KR;
      float acc;
      if (n % KR == KR - 1) {      // root: attention-weighted sum of 12 srcs
        acc = 0.f;
#pragma unroll
        for (int kp = 0; kp < KLEAF; kp++) acc += alph[m2][kp] * Hm[m2 * KR + kp][oc];
#pragma unroll
        for (int j = 0; j < 7; j++) {
          int mm = j < m2 ? j : j + 1;
          acc += alph[m2][KLEAF + j] * Hm[mm * KR + KR - 1][oc];
        }
      } else {                      // leaf: single incoming edge, alpha == 1
        acc = Hm[m2 * KR + KR - 1][oc];
      }
      acc += bias[oc];
      hv[rep] = acc > 0.f ? acc : __expf(acc) - 1.f;   // elu
    }
    __syncthreads();
#pragma unroll
    for (int rep = 0; rep < 6; rep++) X[n0 + rep * 8][oc] = hv[rep];
    __syncthreads();
  }
  for (int i = tid; i < N * H; i += 256)
    gat_ws[((size_t)t * BNR + (size_t)b * N) * H + i] = ((float*)X)[i];
}

extern "C" void kernel_launch(void* const* d_in, const int* in_sizes, int n_in,
                              void* d_out, int out_size, void* d_ws, size_t ws_size,
                              hipStream_t stream)
{
  const float* feat     = (const float*)d_in[0];
  const float* phi_w1   = (const float*)d_in[1];
  const float* phi_b1   = (const float*)d_in[2];
  const float* phi_w2   = (const float*)d_in[3];
  const float* phi_b2   = (const float*)d_in[4];
  const float* spa_wih  = (const float*)d_in[5];
  const float* spa_whh  = (const float*)d_in[6];
  const float* spa_bih  = (const float*)d_in[7];
  const float* spa_bhh  = (const float*)d_in[8];
  const float* bn_gamma = (const float*)d_in[9];
  const float* bn_beta  = (const float*)d_in[10];
  const float* gat1_w   = (const float*)d_in[11];
  const float* gat1_a   = (const float*)d_in[12];
  const float* gat1_b   = (const float*)d_in[13];
  const float* gat2_w   = (const float*)d_in[14];
  const float* gat2_a   = (const float*)d_in[15];
  const float* gat2_b   = (const float*)d_in[16];
  const float* temp_wih = (const float*)d_in[17];
  const float* temp_whh = (const float*)d_in[18];
  const float* temp_bih = (const float*)d_in[19];
  const float* temp_bhh = (const float*)d_in[20];
  float* out = (float*)d_out;

  float* v_ws   = (float*)d_ws;                     // T*BNR*E   = 6.29M floats
  float* bn_ws  = v_ws  + (size_t)T * BNR * E;      // B*T*N*H   = 12.58M floats
  float* gat_ws = bn_ws + (size_t)B * T * N * H;    // T*BNR*H   = 12.58M floats

  k_phi  <<<(B * T * N + 255) / 256, 256, 0, stream>>>(feat, phi_w1, phi_b1, phi_w2, phi_b2, v_ws);
  k_lstm<16, 0><<<BNR, 64, 0, stream>>>(v_ws, spa_wih, spa_whh, spa_bih, spa_bhh, out);
  k_bn   <<<T, 256, 0, stream>>>(out, bn_gamma, bn_beta, bn_ws);
  k_gat  <<<NG, 256, 0, stream>>>(bn_ws, gat1_w, gat1_a, gat1_b, gat2_w, gat2_a, gat2_b, gat_ws);
  k_lstm<32, 1><<<BNR, 64, 0, stream>>>(gat_ws, temp_wih, temp_whh, temp_bih, temp_bhh, out);
}

// Round 3
// 430.711 us; speedup vs baseline: 2.6585x; 1.3740x over previous
//
#include <hip/hip_runtime.h>

constexpr int B = 64, T = 128, M = 8, KLEAF = 5, KR = 6, N = 48, E = 16, H = 32;
constexpr int BNR = B * N;              // 3072 rows
constexpr int NG  = B * T;              // 8192 graphs
constexpr int BNP = 16;                 // BN stat partitions
constexpr long long R_SIZE = (long long)B * T * N * H;  // 12582912

#define DEVI __device__ __forceinline__

DEVI float frcp(float x) { return __builtin_amdgcn_rcpf(x); }
DEVI float sigm(float x) { return frcp(1.f + __expf(-x)); }
DEVI float tanh_(float x) {
  float a = __expf(2.f * fabsf(x));
  float r = 1.f - 2.f * frcp(a + 1.f);
  return x >= 0.f ? r : -r;
}

// ---------------- K1: root aggregation + phi MLP → v_ws (T, B*N, E) ----------
__global__ __launch_bounds__(256) void k_phi(
    const float* __restrict__ feat, const float* __restrict__ w1,
    const float* __restrict__ b1, const float* __restrict__ w2,
    const float* __restrict__ b2, float* __restrict__ v_ws)
{
  int gid = blockIdx.x * 256 + threadIdx.x;
  if (gid >= B * T * N) return;
  int nn = gid % N;        // node within graph = m*KR + k
  int bt = gid / N;        // b*T + t
  int m = nn / KR, k = nn % KR;
  int t = bt % T, b = bt / T;
  const float* fp = feat + ((size_t)bt * M + m) * (KLEAF * 3);
  float x0, x1, x2;
  if (k < KLEAF) {
    x0 = fp[k * 3 + 0]; x1 = fp[k * 3 + 1]; x2 = fp[k * 3 + 2];
  } else {
    float sx = 0.f, sy = 0.f, sw = 0.f, av = 0.f;
#pragma unroll
    for (int kp = 0; kp < KLEAF; kp++) {
      float fx = fp[kp * 3], fy = fp[kp * 3 + 1], fv = fp[kp * 3 + 2];
      float w = fv > 0.5f ? 1.f : 0.f;
      sx += fx * w; sy += fy * w; sw += w; av = fmaxf(av, w);
    }
    float dn = fmaxf(sw, 1.f);
    x0 = sx / dn; x1 = sy / dn; x2 = av;
  }
  float hd[E];
#pragma unroll
  for (int e = 0; e < E; e++) {
    float v = b1[e] + x0 * w1[0 * E + e] + x1 * w1[1 * E + e] + x2 * w1[2 * E + e];
    hd[e] = v > 0.f ? v : 0.f;
  }
  float* vo = v_ws + ((size_t)t * BNR + (size_t)b * N + nn) * E;
#pragma unroll
  for (int e2 = 0; e2 < E; e2++) {
    float acc = b2[e2];
#pragma unroll
    for (int e = 0; e < E; e++) acc += hd[e] * w2[e * E + e2];
    vo[e2] = acc;
  }
}

// ------------- K2/K5: LSTM, 1 row per 64-lane wave ---------------------------
// lane L: j = L&31, hi = L>>5. Lane computes gate rows gA = hi*32+j (i or f)
// and gB = 64+hi*32+j (g or o). h broadcast via per-wave LDS slot (in-order DS
// within one wave -> no barrier). Weights MUST stay in VGPRs: step body is a
// macro with compile-time-constant array indexing (no lambda, no pointer
// passing -> mem2reg keeps arrays in registers).
#define LSTM_STEP(PF, XCUR, XNXT)                                             \
  {                                                                           \
    if (PF) {                                                                 \
      _Pragma("unroll")                                                       \
      for (int q = 0; q < X4; q++) XNXT[q] = xptr[q];                         \
      xptr += XSTRIDE;                                                        \
    }                                                                         \
    float aA0 = bsA, aA1 = 0.f, aB0 = bsB, aB1 = 0.f;                         \
    _Pragma("unroll")                                                         \
    for (int q = 0; q < X4; q++) {                                            \
      float4 xv = XCUR[q];                                                    \
      aA0 += WxA[4 * q + 0] * xv.x; aA1 += WxA[4 * q + 1] * xv.y;             \
      aA0 += WxA[4 * q + 2] * xv.z; aA1 += WxA[4 * q + 3] * xv.w;             \
      aB0 += WxB[4 * q + 0] * xv.x; aB1 += WxB[4 * q + 1] * xv.y;             \
      aB0 += WxB[4 * q + 2] * xv.z; aB1 += WxB[4 * q + 3] * xv.w;             \
    }                                                                         \
    _Pragma("unroll")                                                         \
    for (int q = 0; q < 8; q++) {                                             \
      float4 hv = ((const float4*)hbuf)[q];                                   \
      aA0 += WhA[4 * q + 0] * hv.x; aA1 += WhA[4 * q + 1] * hv.y;             \
      aA0 += WhA[4 * q + 2] * hv.z; aA1 += WhA[4 * q + 3] * hv.w;             \
      aB0 += WhB[4 * q + 0] * hv.x; aB1 += WhB[4 * q + 1] * hv.y;             \
      aB0 += WhB[4 * q + 2] * hv.z; aB1 += WhB[4 * q + 3] * hv.w;             \
    }                                                                         \
    float aA = aA0 + aA1, aB = aB0 + aB1;                                     \
    float sA = sigm(aA);                       /* lo: sigm(i); hi: sigm(f) */ \
    float vB = hi ? sigm(aB) : tanh_(aB);      /* lo: tanh(g); hi: sigm(o) */ \
    float send = hi ? sA : sA * vB;            /* hi sends f; lo sends i*g */ \
    float recv = __shfl_xor(send, 32);                                        \
    float sF = hi ? sA : recv;                                                \
    float p2 = hi ? recv : send;                                              \
    c = sF * c + p2;                                                          \
    float tc = tanh_(c);                                                      \
    if (hi) {                                                                 \
      float hnew = vB * tc;                                                   \
      hbuf[j] = hnew;                                                         \
      if (MODE == 0) { *pr = hnew; *ph = hnew; }                              \
      else { *ph = hnew; }                                                    \
    }                                                                         \
    pr += N * H; ph += N * 2 * H;                                             \
    __builtin_amdgcn_sched_barrier(0);                                        \
  }

template <int EE, int MODE>
__global__ void __launch_bounds__(64, 2) k_lstm(
    const float* __restrict__ x, const float* __restrict__ wih,
    const float* __restrict__ whh, const float* __restrict__ bih,
    const float* __restrict__ bhh, float* __restrict__ dout)
{
  constexpr int X4 = EE / 4;
  int j = threadIdx.x & 31, hi = threadIdx.x >> 5;
  int row = blockIdx.x;
  int b = row / N, n = row % N;
  int gA = hi * 32 + j, gB = 64 + hi * 32 + j;

  float WxA[EE], WxB[EE], WhA[32], WhB[32];
#pragma unroll
  for (int e = 0; e < EE; e++) { WxA[e] = wih[gA * EE + e]; WxB[e] = wih[gB * EE + e]; }
#pragma unroll
  for (int k = 0; k < 32; k++) { WhA[k] = whh[gA * 32 + k]; WhB[k] = whh[gB * 32 + k]; }
  float bsA = bih[gA] + bhh[gA], bsB = bih[gB] + bhh[gB];

  __shared__ __align__(16) float hbuf[32];
  if (threadIdx.x < 32) hbuf[threadIdx.x] = 0.f;   // same wave: in-order DS

  float c = 0.f;
  constexpr size_t XSTRIDE = (size_t)BNR * EE / 4;   // per-t stride in float4
  const float4* xptr = (const float4*)(x + (size_t)row * EE);

  float* pr = dout + ((size_t)b * T * N + n) * H + j;
  float* ph = dout + R_SIZE + ((size_t)b * T * N + n) * 2 * H + (MODE == 1 ? H : 0) + j;

  float4 XC[X4], XN[X4];
#pragma unroll
  for (int q = 0; q < X4; q++) XC[q] = xptr[q];
  xptr += XSTRIDE;                                   // points at t=1

  for (int t = 0; t < T - 2; t += 2) {
    LSTM_STEP(true, XC, XN);
    LSTM_STEP(true, XN, XC);
  }
  LSTM_STEP(true, XC, XN);    // t = T-2, prefetches t = T-1
  LSTM_STEP(false, XN, XC);   // t = T-1, no prefetch
}

// ---------------- K3a: BN partial stats per (t, partition) -------------------
__global__ __launch_bounds__(256) void k_bn1(
    const float* __restrict__ r, float* __restrict__ part)
{
  int t = blockIdx.x, p = blockIdx.y;
  int c = threadIdx.x & 31, rg = threadIdx.x >> 5;
  constexpr int RPP = BNR / BNP;   // 192 rows per partition
  float s = 0.f, s2 = 0.f;
  for (int row = p * RPP + rg; row < (p + 1) * RPP; row += 8) {
    int b = row / N, n = row % N;
    float x = r[((size_t)b * T + t) * N * H + (size_t)n * H + c];
    s += x; s2 += x * x;
  }
  __shared__ float sm[2][8][32];
  sm[0][rg][c] = s; sm[1][rg][c] = s2;
  __syncthreads();
  if (rg == 0) {
    float ss = 0.f, ss2 = 0.f;
#pragma unroll
    for (int i = 0; i < 8; i++) { ss += sm[0][i][c]; ss2 += sm[1][i][c]; }
    part[((size_t)t * BNP + p) * 64 + c] = ss;
    part[((size_t)t * BNP + p) * 64 + 32 + c] = ss2;
  }
}

// ---------------- K3b: finalize BN scale/shift table (T, 2, 32) --------------
__global__ void k_bn2(
    const float* __restrict__ part, const float* __restrict__ gamma,
    const float* __restrict__ beta, float* __restrict__ sctab)
{
  int t = blockIdx.x, c = threadIdx.x;   // 32 threads
  float ss = 0.f, ss2 = 0.f;
#pragma unroll
  for (int p = 0; p < BNP; p++) {
    ss  += part[((size_t)t * BNP + p) * 64 + c];
    ss2 += part[((size_t)t * BNP + p) * 64 + 32 + c];
  }
  float mu = ss * (1.f / BNR);
  float var = ss2 * (1.f / BNR) - mu * mu;
  float rstd = rsqrtf(var + 1e-5f);
  float sc = gamma[c] * rstd;
  sctab[t * 64 + c] = sc;
  sctab[t * 64 + 32 + c] = beta[c] - mu * sc;
}

// ------------- K4: fused BN-apply + 2x GAT per graph → gat_ws (T,B*N,H) ------
__global__ __launch_bounds__(256) void k_gat(
    const float* __restrict__ r, const float* __restrict__ sctab,
    const float* __restrict__ w1, const float* __restrict__ a1, const float* __restrict__ bg1,
    const float* __restrict__ w2, const float* __restrict__ a2, const float* __restrict__ bg2,
    float* __restrict__ gat_ws)
{
  int g = blockIdx.x;          // b*T + t
  int b = g >> 7, t = g & 127;
  int tid = threadIdx.x;
  __shared__ float X[N][H];
  __shared__ float Hm[N][H + 1];   // padded: row-reads conflict-free
  __shared__ float Wl[H * H];
  __shared__ float ssrc[N], sdst[N];
  __shared__ float alph[M][12];
  for (int i = tid; i < N * H; i += 256) {
    int cc = i & 31;
    ((float*)X)[i] = r[(size_t)g * N * H + i] * sctab[t * 64 + cc] + sctab[t * 64 + 32 + cc];
  }
  const float* Ws[2] = {w1, w2};
  const float* As[2] = {a1, a2};
  const float* Bs[2] = {bg1, bg2};
  int oc = tid & 31, n0 = tid >> 5;
  for (int layer = 0; layer < 2; layer++) {
    const float* av = As[layer];
    const float* bias = Bs[layer];
    for (int i = tid; i < H * H; i += 256) Wl[i] = Ws[layer][i];
    __syncthreads();
    // h = X @ W  (48x32 @ 32x32)
#pragma unroll
    for (int rep = 0; rep < 6; rep++) {
      int n = n0 + rep * 8;
      float acc = 0.f;
#pragma unroll
      for (int kk = 0; kk < H; kk++) acc += X[n][kk] * Wl[kk * H + oc];
      Hm[n][oc] = acc;
    }
    __syncthreads();
    if (tid < N) {
      float as = 0.f, ad = 0.f;
#pragma unroll
      for (int kk = 0; kk < H; kk++) {
        float x = Hm[tid][kk];
        as += x * av[kk]; ad += x * av[H + kk];
      }
      ssrc[tid] = as; sdst[tid] = ad;
    }
    __syncthreads();
    if (tid < M) {   // softmax over each root's 12 incoming edges
      float ev[12];
      float sd = sdst[tid * KR + KR - 1];
#pragma unroll
      for (int kp = 0; kp < KLEAF; kp++) ev[kp] = ssrc[tid * KR + kp] + sd;
#pragma unroll
      for (int j = 0; j < 7; j++) {
        int mm = j < tid ? j : j + 1;
        ev[KLEAF + j] = ssrc[mm * KR + KR - 1] + sd;
      }
      float mx = -1e30f;
#pragma unroll
      for (int i = 0; i < 12; i++) {
        float e = ev[i]; e = e > 0.f ? e : 0.2f * e;
        ev[i] = e; mx = fmaxf(mx, e);
      }
      float s = 0.f;
#pragma unroll
      for (int i = 0; i < 12; i++) { float e = __expf(ev[i] - mx); ev[i] = e; s += e; }
      float inv = frcp(s);
#pragma unroll
      for (int i = 0; i < 12; i++) alph[tid][i] = ev[i] * inv;
    }
    __syncthreads();
    float hv[6];
#pragma unroll
    for (int rep = 0; rep < 6; rep++) {
      int n = n0 + rep * 8;
      int m2 = n / KR;
      float acc;
      if (n % KR == KR - 1) {      // root: attention-weighted sum of 12 srcs
        acc = 0.f;
#pragma unroll
        for (int kp = 0; kp < KLEAF; kp++) acc += alph[m2][kp] * Hm[m2 * KR + kp][oc];
#pragma unroll
        for (int j = 0; j < 7; j++) {
          int mm = j < m2 ? j : j + 1;
          acc += alph[m2][KLEAF + j] * Hm[mm * KR + KR - 1][oc];
        }
      } else {                      // leaf: single incoming edge, alpha == 1
        acc = Hm[m2 * KR + KR - 1][oc];
      }
      acc += bias[oc];
      hv[rep] = acc > 0.f ? acc : __expf(acc) - 1.f;   // elu
    }
    __syncthreads();
#pragma unroll
    for (int rep = 0; rep < 6; rep++) X[n0 + rep * 8][oc] = hv[rep];
    __syncthreads();
  }
  for (int i = tid; i < N * H; i += 256)
    gat_ws[((size_t)t * BNR + (size_t)b * N) * H + i] = ((float*)X)[i];
}

extern "C" void kernel_launch(void* const* d_in, const int* in_sizes, int n_in,
                              void* d_out, int out_size, void* d_ws, size_t ws_size,
                              hipStream_t stream)
{
  const float* feat     = (const float*)d_in[0];
  const float* phi_w1   = (const float*)d_in[1];
  const float* phi_b1   = (const float*)d_in[2];
  const float* phi_w2   = (const float*)d_in[3];
  const float* phi_b2   = (const float*)d_in[4];
  const float* spa_wih  = (const float*)d_in[5];
  const float* spa_whh  = (const float*)d_in[6];
  const float* spa_bih  = (const float*)d_in[7];
  const float* spa_bhh  = (const float*)d_in[8];
  const float* bn_gamma = (const float*)d_in[9];
  const float* bn_beta  = (const float*)d_in[10];
  const float* gat1_w   = (const float*)d_in[11];
  const float* gat1_a   = (const float*)d_in[12];
  const float* gat1_b   = (const float*)d_in[13];
  const float* gat2_w   = (const float*)d_in[14];
  const float* gat2_a   = (const float*)d_in[15];
  const float* gat2_b   = (const float*)d_in[16];
  const float* temp_wih = (const float*)d_in[17];
  const float* temp_whh = (const float*)d_in[18];
  const float* temp_bih = (const float*)d_in[19];
  const float* temp_bhh = (const float*)d_in[20];
  float* out = (float*)d_out;

  float* v_ws   = (float*)d_ws;                     // T*BNR*E   = 6.29M floats
  float* gat_ws = v_ws   + (size_t)T * BNR * E;     // T*BNR*H   = 12.58M floats
  float* bnpart = gat_ws + (size_t)T * BNR * H;     // T*BNP*64  = 131072 floats
  float* sctab  = bnpart + (size_t)T * BNP * 64;    // T*64      = 8192 floats

  k_phi <<<(B * T * N + 255) / 256, 256, 0, stream>>>(feat, phi_w1, phi_b1, phi_w2, phi_b2, v_ws);
  k_lstm<16, 0><<<BNR, 64, 0, stream>>>(v_ws, spa_wih, spa_whh, spa_bih, spa_bhh, out);
  k_bn1 <<<dim3(T, BNP), 256, 0, stream>>>(out, bnpart);
  k_bn2 <<<T, 32, 0, stream>>>(bnpart, bn_gamma, bn_beta, sctab);
  k_gat <<<NG, 256, 0, stream>>>(out, sctab, gat1_w, gat1_a, gat1_b, gat2_w, gat2_a, gat2_b, gat_ws);
  k_lstm<32, 1><<<BNR, 64, 0, stream>>>(gat_ws, temp_wih, temp_whh, temp_bih, temp_bhh, out);
}

// Round 4
// 429.630 us; speedup vs baseline: 2.6652x; 1.0025x over previous
//
#include <hip/hip_runtime.h>

constexpr int B = 64, T = 128, M = 8, KLEAF = 5, KR = 6, N = 48, E = 16, H = 32;
constexpr int BNR = B * N;              // 3072 rows
constexpr int NG  = B * T;              // 8192 graphs
constexpr int BNP = 16;                 // BN stat partitions
constexpr long long R_SIZE = (long long)B * T * N * H;  // 12582912

#define DEVI __device__ __forceinline__

DEVI float frcp(float x) { return __builtin_amdgcn_rcpf(x); }
DEVI float sigm(float x) { return frcp(1.f + __expf(-x)); }
DEVI float tanh_(float x) {
  float a = __expf(2.f * fabsf(x));
  float r = 1.f - 2.f * frcp(a + 1.f);
  return x >= 0.f ? r : -r;
}

// ---------------- K1: root aggregation + phi MLP → v_ws (T, B*N, E) ----------
__global__ __launch_bounds__(256) void k_phi(
    const float* __restrict__ feat, const float* __restrict__ w1,
    const float* __restrict__ b1, const float* __restrict__ w2,
    const float* __restrict__ b2, float* __restrict__ v_ws)
{
  int gid = blockIdx.x * 256 + threadIdx.x;
  if (gid >= B * T * N) return;
  int nn = gid % N;        // node within graph = m*KR + k
  int bt = gid / N;        // b*T + t
  int m = nn / KR, k = nn % KR;
  int t = bt % T, b = bt / T;
  const float* fp = feat + ((size_t)bt * M + m) * (KLEAF * 3);
  float x0, x1, x2;
  if (k < KLEAF) {
    x0 = fp[k * 3 + 0]; x1 = fp[k * 3 + 1]; x2 = fp[k * 3 + 2];
  } else {
    float sx = 0.f, sy = 0.f, sw = 0.f, av = 0.f;
#pragma unroll
    for (int kp = 0; kp < KLEAF; kp++) {
      float fx = fp[kp * 3], fy = fp[kp * 3 + 1], fv = fp[kp * 3 + 2];
      float w = fv > 0.5f ? 1.f : 0.f;
      sx += fx * w; sy += fy * w; sw += w; av = fmaxf(av, w);
    }
    float dn = fmaxf(sw, 1.f);
    x0 = sx / dn; x1 = sy / dn; x2 = av;
  }
  float hd[E];
#pragma unroll
  for (int e = 0; e < E; e++) {
    float v = b1[e] + x0 * w1[0 * E + e] + x1 * w1[1 * E + e] + x2 * w1[2 * E + e];
    hd[e] = v > 0.f ? v : 0.f;
  }
  float* vo = v_ws + ((size_t)t * BNR + (size_t)b * N + nn) * E;
#pragma unroll
  for (int e2 = 0; e2 < E; e2++) {
    float acc = b2[e2];
#pragma unroll
    for (int e = 0; e < E; e++) acc += hd[e] * w2[e * E + e2];
    vo[e2] = acc;
  }
}

// ------------- K2/K5: LSTM, 1 row per 64-lane wave ---------------------------
// lane L: j = L&31, hi = L>>5. Lane computes gate rows gA = hi*32+j (i or f)
// and gB = 64+hi*32+j (g or o). h broadcast via per-wave LDS slot (in-order DS
// within one wave -> no barrier). Weights pinned into VGPRs via empty inline
// asm ("+v") after load: the compiler cannot rematerialize an asm result, so
// the 96/128 weight values stay register-resident across the whole t-loop.
#define LSTM_STEP(PF, XCUR, XNXT)                                             \
  {                                                                           \
    if (PF) {                                                                 \
      _Pragma("unroll")                                                       \
      for (int q = 0; q < X4; q++) XNXT[q] = xptr[q];                         \
      xptr += XSTRIDE;                                                        \
    }                                                                         \
    float aA0 = bsA, aA1 = 0.f, aA2 = 0.f, aA3 = 0.f;                         \
    float aB0 = bsB, aB1 = 0.f, aB2 = 0.f, aB3 = 0.f;                         \
    _Pragma("unroll")                                                         \
    for (int q = 0; q < X4; q++) {                                            \
      float4 xv = XCUR[q];                                                    \
      aA0 += WxA[4 * q + 0] * xv.x; aA1 += WxA[4 * q + 1] * xv.y;             \
      aA2 += WxA[4 * q + 2] * xv.z; aA3 += WxA[4 * q + 3] * xv.w;             \
      aB0 += WxB[4 * q + 0] * xv.x; aB1 += WxB[4 * q + 1] * xv.y;             \
      aB2 += WxB[4 * q + 2] * xv.z; aB3 += WxB[4 * q + 3] * xv.w;             \
    }                                                                         \
    _Pragma("unroll")                                                         \
    for (int q = 0; q < 8; q++) {                                             \
      float4 hv = ((const float4*)hbuf)[q];                                   \
      aA0 += WhA[4 * q + 0] * hv.x; aA1 += WhA[4 * q + 1] * hv.y;             \
      aA2 += WhA[4 * q + 2] * hv.z; aA3 += WhA[4 * q + 3] * hv.w;             \
      aB0 += WhB[4 * q + 0] * hv.x; aB1 += WhB[4 * q + 1] * hv.y;             \
      aB2 += WhB[4 * q + 2] * hv.z; aB3 += WhB[4 * q + 3] * hv.w;             \
    }                                                                         \
    float aA = (aA0 + aA1) + (aA2 + aA3);                                     \
    float aB = (aB0 + aB1) + (aB2 + aB3);                                     \
    float sA = sigm(aA);                       /* lo: sigm(i); hi: sigm(f) */ \
    float vB = hi ? sigm(aB) : tanh_(aB);      /* lo: tanh(g); hi: sigm(o) */ \
    float send = hi ? sA : sA * vB;            /* hi sends f; lo sends i*g */ \
    float recv = __shfl_xor(send, 32);                                        \
    float sF = hi ? sA : recv;                                                \
    float p2 = hi ? recv : send;                                              \
    c = sF * c + p2;                                                          \
    float tc = tanh_(c);                                                      \
    if (hi) {                                                                 \
      float hnew = vB * tc;                                                   \
      hbuf[j] = hnew;                                                         \
      if (MODE == 0) { *pr = hnew; *ph = hnew; }                              \
      else { *ph = hnew; }                                                    \
    }                                                                         \
    pr += N * H; ph += N * 2 * H;                                             \
  }

template <int EE, int MODE>
__global__ void __launch_bounds__(64, 1) k_lstm(
    const float* __restrict__ x, const float* __restrict__ wih,
    const float* __restrict__ whh, const float* __restrict__ bih,
    const float* __restrict__ bhh, float* __restrict__ dout)
{
  constexpr int X4 = EE / 4;
  int j = threadIdx.x & 31, hi = threadIdx.x >> 5;
  int row = blockIdx.x;
  int b = row / N, n = row % N;
  int gA = hi * 32 + j, gB = 64 + hi * 32 + j;

  float WxA[EE], WxB[EE], WhA[32], WhB[32];
#pragma unroll
  for (int e = 0; e < EE; e++) { WxA[e] = wih[gA * EE + e]; WxB[e] = wih[gB * EE + e]; }
#pragma unroll
  for (int k = 0; k < 32; k++) { WhA[k] = whh[gA * 32 + k]; WhB[k] = whh[gB * 32 + k]; }
  float bsA = bih[gA] + bhh[gA], bsB = bih[gB] + bhh[gB];
  // Pin every weight into a VGPR: opaque to remat/sink, forces residency.
#pragma unroll
  for (int e = 0; e < EE; e++) {
    asm volatile("" : "+v"(WxA[e]));
    asm volatile("" : "+v"(WxB[e]));
  }
#pragma unroll
  for (int k = 0; k < 32; k++) {
    asm volatile("" : "+v"(WhA[k]));
    asm volatile("" : "+v"(WhB[k]));
  }

  __shared__ __align__(16) float hbuf[32];
  if (threadIdx.x < 32) hbuf[threadIdx.x] = 0.f;   // same wave: in-order DS

  float c = 0.f;
  constexpr size_t XSTRIDE = (size_t)BNR * EE / 4;   // per-t stride in float4
  const float4* xptr = (const float4*)(x + (size_t)row * EE);

  float* pr = dout + ((size_t)b * T * N + n) * H + j;
  float* ph = dout + R_SIZE + ((size_t)b * T * N + n) * 2 * H + (MODE == 1 ? H : 0) + j;

  float4 XC[X4], XN[X4];
#pragma unroll
  for (int q = 0; q < X4; q++) XC[q] = xptr[q];
  xptr += XSTRIDE;                                   // points at t=1

  for (int t = 0; t < T - 2; t += 2) {
    LSTM_STEP(true, XC, XN);
    LSTM_STEP(true, XN, XC);
  }
  LSTM_STEP(true, XC, XN);    // t = T-2, prefetches t = T-1
  LSTM_STEP(false, XN, XC);   // t = T-1, no prefetch
}

// ---------------- K3a: BN partial stats per (t, partition) -------------------
__global__ __launch_bounds__(256) void k_bn1(
    const float* __restrict__ r, float* __restrict__ part)
{
  int t = blockIdx.x, p = blockIdx.y;
  int c = threadIdx.x & 31, rg = threadIdx.x >> 5;
  constexpr int RPP = BNR / BNP;   // 192 rows per partition
  float s = 0.f, s2 = 0.f;
  for (int row = p * RPP + rg; row < (p + 1) * RPP; row += 8) {
    int b = row / N, n = row % N;
    float x = r[((size_t)b * T + t) * N * H + (size_t)n * H + c];
    s += x; s2 += x * x;
  }
  __shared__ float sm[2][8][32];
  sm[0][rg][c] = s; sm[1][rg][c] = s2;
  __syncthreads();
  if (rg == 0) {
    float ss = 0.f, ss2 = 0.f;
#pragma unroll
    for (int i = 0; i < 8; i++) { ss += sm[0][i][c]; ss2 += sm[1][i][c]; }
    part[((size_t)t * BNP + p) * 64 + c] = ss;
    part[((size_t)t * BNP + p) * 64 + 32 + c] = ss2;
  }
}

// ---------------- K3b: finalize BN scale/shift table (T, 2, 32) --------------
__global__ void k_bn2(
    const float* __restrict__ part, const float* __restrict__ gamma,
    const float* __restrict__ beta, float* __restrict__ sctab)
{
  int t = blockIdx.x, c = threadIdx.x;   // 32 threads
  float ss = 0.f, ss2 = 0.f;
#pragma unroll
  for (int p = 0; p < BNP; p++) {
    ss  += part[((size_t)t * BNP + p) * 64 + c];
    ss2 += part[((size_t)t * BNP + p) * 64 + 32 + c];
  }
  float mu = ss * (1.f / BNR);
  float var = ss2 * (1.f / BNR) - mu * mu;
  float rstd = rsqrtf(var + 1e-5f);
  float sc = gamma[c] * rstd;
  sctab[t * 64 + c] = sc;
  sctab[t * 64 + 32 + c] = beta[c] - mu * sc;
}

// ------------- K4: fused BN-apply + 2x GAT per graph → gat_ws (T,B*N,H) ------
__global__ __launch_bounds__(256) void k_gat(
    const float* __restrict__ r, const float* __restrict__ sctab,
    const float* __restrict__ w1, const float* __restrict__ a1, const float* __restrict__ bg1,
    const float* __restrict__ w2, const float* __restrict__ a2, const float* __restrict__ bg2,
    float* __restrict__ gat_ws)
{
  int g = blockIdx.x;          // b*T + t
  int b = g >> 7, t = g & 127;
  int tid = threadIdx.x;
  __shared__ float X[N][H];
  __shared__ float Hm[N][H + 1];   // padded: row-reads conflict-free
  __shared__ float Wl[H * H];
  __shared__ float ssrc[N], sdst[N];
  __shared__ float alph[M][12];
  for (int i = tid; i < N * H; i += 256) {
    int cc = i & 31;
    ((float*)X)[i] = r[(size_t)g * N * H + i] * sctab[t * 64 + cc] + sctab[t * 64 + 32 + cc];
  }
  const float* Ws[2] = {w1, w2};
  const float* As[2] = {a1, a2};
  const float* Bs[2] = {bg1, bg2};
  int oc = tid & 31, n0 = tid >> 5;
  for (int layer = 0; layer < 2; layer++) {
    const float* av = As[layer];
    const float* bias = Bs[layer];
    for (int i = tid; i < H * H; i += 256) Wl[i] = Ws[layer][i];
    __syncthreads();
    // h = X @ W  (48x32 @ 32x32)
#pragma unroll
    for (int rep = 0; rep < 6; rep++) {
      int n = n0 + rep * 8;
      float acc = 0.f;
#pragma unroll
      for (int kk = 0; kk < H; kk++) acc += X[n][kk] * Wl[kk * H + oc];
      Hm[n][oc] = acc;
    }
    __syncthreads();
    if (tid < N) {
      float as = 0.f, ad = 0.f;
#pragma unroll
      for (int kk = 0; kk < H; kk++) {
        float x = Hm[tid][kk];
        as += x * av[kk]; ad += x * av[H + kk];
      }
      ssrc[tid] = as; sdst[tid] = ad;
    }
    __syncthreads();
    if (tid < M) {   // softmax over each root's 12 incoming edges
      float ev[12];
      float sd = sdst[tid * KR + KR - 1];
#pragma unroll
      for (int kp = 0; kp < KLEAF; kp++) ev[kp] = ssrc[tid * KR + kp] + sd;
#pragma unroll
      for (int j = 0; j < 7; j++) {
        int mm = j < tid ? j : j + 1;
        ev[KLEAF + j] = ssrc[mm * KR + KR - 1] + sd;
      }
      float mx = -1e30f;
#pragma unroll
      for (int i = 0; i < 12; i++) {
        float e = ev[i]; e = e > 0.f ? e : 0.2f * e;
        ev[i] = e; mx = fmaxf(mx, e);
      }
      float s = 0.f;
#pragma unroll
      for (int i = 0; i < 12; i++) { float e = __expf(ev[i] - mx); ev[i] = e; s += e; }
      float inv = frcp(s);
#pragma unroll
      for (int i = 0; i < 12; i++) alph[tid][i] = ev[i] * inv;
    }
    __syncthreads();
    float hv[6];
#pragma unroll
    for (int rep = 0; rep < 6; rep++) {
      int n = n0 + rep * 8;
      int m2 = n / KR;
      float acc;
      if (n % KR == KR - 1) {      // root: attention-weighted sum of 12 srcs
        acc = 0.f;
#pragma unroll
        for (int kp = 0; kp < KLEAF; kp++) acc += alph[m2][kp] * Hm[m2 * KR + kp][oc];
#pragma unroll
        for (int j = 0; j < 7; j++) {
          int mm = j < m2 ? j : j + 1;
          acc += alph[m2][KLEAF + j] * Hm[mm * KR + KR - 1][oc];
        }
      } else {                      // leaf: single incoming edge, alpha == 1
        acc = Hm[m2 * KR + KR - 1][oc];
      }
      acc += bias[oc];
      hv[rep] = acc > 0.f ? acc : __expf(acc) - 1.f;   // elu
    }
    __syncthreads();
#pragma unroll
    for (int rep = 0; rep < 6; rep++) X[n0 + rep * 8][oc] = hv[rep];
    __syncthreads();
  }
  for (int i = tid; i < N * H; i += 256)
    gat_ws[((size_t)t * BNR + (size_t)b * N) * H + i] = ((float*)X)[i];
}

extern "C" void kernel_launch(void* const* d_in, const int* in_sizes, int n_in,
                              void* d_out, int out_size, void* d_ws, size_t ws_size,
                              hipStream_t stream)
{
  const float* feat     = (const float*)d_in[0];
  const float* phi_w1   = (const float*)d_in[1];
  const float* phi_b1   = (const float*)d_in[2];
  const float* phi_w2   = (const float*)d_in[3];
  const float* phi_b2   = (const float*)d_in[4];
  const float* spa_wih  = (const float*)d_in[5];
  const float* spa_whh  = (const float*)d_in[6];
  const float* spa_bih  = (const float*)d_in[7];
  const float* spa_bhh  = (const float*)d_in[8];
  const float* bn_gamma = (const float*)d_in[9];
  const float* bn_beta  = (const float*)d_in[10];
  const float* gat1_w   = (const float*)d_in[11];
  const float* gat1_a   = (const float*)d_in[12];
  const float* gat1_b   = (const float*)d_in[13];
  const float* gat2_w   = (const float*)d_in[14];
  const float* gat2_a   = (const float*)d_in[15];
  const float* gat2_b   = (const float*)d_in[16];
  const float* temp_wih = (const float*)d_in[17];
  const float* temp_whh = (const float*)d_in[18];
  const float* temp_bih = (const float*)d_in[19];
  const float* temp_bhh = (const float*)d_in[20];
  float* out = (float*)d_out;

  float* v_ws   = (float*)d_ws;                     // T*BNR*E   = 6.29M floats
  float* gat_ws = v_ws   + (size_t)T * BNR * E;     // T*BNR*H   = 12.58M floats
  float* bnpart = gat_ws + (size_t)T * BNR * H;     // T*BNP*64  = 131072 floats
  float* sctab  = bnpart + (size_t)T * BNP * 64;    // T*64      = 8192 floats

  k_phi <<<(B * T * N + 255) / 256, 256, 0, stream>>>(feat, phi_w1, phi_b1, phi_w2, phi_b2, v_ws);
  k_lstm<16, 0><<<BNR, 64, 0, stream>>>(v_ws, spa_wih, spa_whh, spa_bih, spa_bhh, out);
  k_bn1 <<<dim3(T, BNP), 256, 0, stream>>>(out, bnpart);
  k_bn2 <<<T, 32, 0, stream>>>(bnpart, bn_gamma, bn_beta, sctab);
  k_gat <<<NG, 256, 0, stream>>>(out, sctab, gat1_w, gat1_a, gat1_b, gat2_w, gat2_a, gat2_b, gat_ws);
  k_lstm<32, 1><<<BNR, 64, 0, stream>>>(gat_ws, temp_wih, temp_whh, temp_bih, temp_bhh, out);
}